// Round 10
// baseline (48.764 us; speedup 1.0000x reference)
//
#include <hip/hip_runtime.h>
#include <hip/hip_bf16.h>
#include <hip/hip_fp16.h>
#include <math.h>

// Problem constants
constexpr int N_    = 2;
constexpr int C_TOT = 256;
constexpr int H_    = 128;
constexpr int W_    = 128;
constexpr int OUTS  = 7;
constexpr int NBIN  = OUTS * OUTS;          // 49
constexpr int NSAMP = NBIN * 4;             // 196 sample points per roi
constexpr int PCH   = C_TOT * NBIN;         // 12544 outputs per roi
constexpr float SCALE = 0.125f;

typedef float f32x4 __attribute__((ext_vector_type(4)));

__device__ __forceinline__ __half2 u2h2(unsigned u) {
  return *reinterpret_cast<__half2*>(&u);
}
__device__ __forceinline__ unsigned h2u(__half2 h) {
  return *reinterpret_cast<unsigned*>(&h);
}

// ---------------------------------------------------------------------------
// NCHW f32 -> NHWC fp16 transpose of features into workspace.
// ---------------------------------------------------------------------------
__global__ __launch_bounds__(256) void transpose_nchw_nhwc_f16(
    const float* __restrict__ in, ushort* __restrict__ out) {
  __shared__ float tile[64][65];
  const int nh = blockIdx.z;
  const int n  = nh >> 7;
  const int h  = nh & 127;
  const int c0 = blockIdx.y * 64;
  const int w0 = blockIdx.x * 64;
  const int tx = threadIdx.x;
  const int ty = threadIdx.y;

  const float* src = in + (((size_t)n * C_TOT + c0) * H_ + h) * W_ + w0;
#pragma unroll
  for (int i = 0; i < 16; ++i) {
    const int c = i * 4 + ty;
    tile[c][tx] = src[(size_t)c * (H_ * W_) + tx];
  }
  __syncthreads();
  ushort* dst = out + (((size_t)n * H_ + h) * W_ + w0) * C_TOT + c0;
#pragma unroll
  for (int i = 0; i < 16; ++i) {
    const int w = i * 4 + ty;
    dst[(size_t)w * C_TOT + tx] = __half_as_ushort(__float2half(tile[tx][w]));
  }
}

// ---------------------------------------------------------------------------
// ROI spatial sort (deterministic bitonic, one block). Sort key: (batch,
// tileY, tileX) of the roi center at 16-px granularity; value: roi index.
// perm[j] = roi index at sorted position j. Requires K <= 1024.
// Purpose: the main kernel assigns contiguous sorted chunks to XCDs, so each
// XCD's gathers target a ~2 MB spatial slice of the 16.8 MB feature map ->
// fits the 4 MB per-XCD L2 (R8 diagnosis: ~20% L2 miss to L3 throttles
// the gather stream).
// ---------------------------------------------------------------------------
__global__ __launch_bounds__(1024) void sort_rois(
    const float* __restrict__ rois, int K, int* __restrict__ perm) {
  __shared__ unsigned a[1024];
  const int t = threadIdx.x;
  unsigned v = 0xFFFFFFFFu;
  if (t < K) {
    const float* roi = rois + (size_t)t * 6;
    const int b  = (int)roi[0];
    const float cx = roi[1] * SCALE;
    const float cy = roi[2] * SCALE;
    int tx = (int)(cx * 0.0625f); tx = tx < 0 ? 0 : (tx > 7 ? 7 : tx);
    int ty = (int)(cy * 0.0625f); ty = ty < 0 ? 0 : (ty > 7 ? 7 : ty);
    const unsigned key = ((unsigned)b << 6) | ((unsigned)ty << 3) | (unsigned)tx;
    v = (key << 10) | (unsigned)t;         // unique -> no ties
  }
  a[t] = v;
  __syncthreads();
  for (int ksz = 2; ksz <= 1024; ksz <<= 1) {
    for (int jsz = ksz >> 1; jsz > 0; jsz >>= 1) {
      const int ixj = t ^ jsz;
      if (ixj > t) {
        const bool up = (t & ksz) == 0;
        const unsigned x = a[t], y = a[ixj];
        if (up ? (x > y) : (x < y)) { a[t] = y; a[ixj] = x; }
      }
      __syncthreads();
    }
  }
  if (t < K) perm[t] = (int)(a[t] & 1023u);
}

__global__ void identity_perm(int K, int* __restrict__ perm) {
  const int i = blockIdx.x * 256 + threadIdx.x;
  if (i < K) perm[i] = i;
}

// ---------------------------------------------------------------------------
// v9 main kernel. Identical compute to v8; adds sorted-roi indirection with
// bijective XCD chunking: block bid -> sorted pos j = chunk(bid%8) + bid/8,
// roi k = perm[j]. Output written to roi k's own slot (order-independent).
// ---------------------------------------------------------------------------
__global__ __launch_bounds__(512, 8) void os2_rroialign_v9(
    const uint4* __restrict__ ft, const float* __restrict__ rois,
    const int* __restrict__ perm, int K, float* __restrict__ out) {
  __shared__ uint2 obuf[NBIN][64];         // 49*512 = 25088 B (fp16 x4)
  __shared__ int4  sIdx[NSAMP];            // 3136 B (uint4-unit pixel base)
  __shared__ uint4 sWh[NSAMP];             // 3136 B (4 dup-half2 weights)

  // bijective XCD chunk map (m204): XCD x gets sorted positions
  // [x<r ? x*(q+1) : r*(q+1)+(x-r)*q, +chunk)
  const int bid = blockIdx.x;
  const int q = K >> 3, r = K & 7;
  const int xcd = bid & 7;
  const int base = xcd < r ? xcd * (q + 1) : r * (q + 1) + (xcd - r) * q;
  const int j = base + (bid >> 3);
  const int k = perm[j];

  const int t = threadIdx.x;

  const float* roi = rois + (size_t)k * 6;
  const float th = roi[5];

  if (t < NSAMP) {
    const int   b  = (int)roi[0];
    const float cx = roi[1] * SCALE;
    const float cy = roi[2] * SCALE;
    const float rw = fmaxf(roi[3] * SCALE, 1.0f);
    const float rh = fmaxf(roi[4] * SCALE, 1.0f);
    const float binw = rw / (float)OUTS;
    const float binh = rh / (float)OUTS;
    const float cs = cosf(th);
    const float sn = sinf(th);

    const int bin = t >> 2;
    const int sub = t & 3;                  // iy*2 + ix
    const int ph  = bin / 7;
    const int pw  = bin - ph * 7;
    const float fy = (float)ph + ((float)(sub >> 1) + 0.5f) * 0.5f;
    const float fx = (float)pw + ((float)(sub & 1)  + 0.5f) * 0.5f;
    const float yy = -rh * 0.5f + fy * binh;
    const float xx = -rw * 0.5f + fx * binw;
    float x = xx * cs - yy * sn + cx;
    float y = xx * sn + yy * cs + cy;
    const bool valid = (y >= -1.0f) && (y <= (float)H_) &&
                       (x >= -1.0f) && (x <= (float)W_);
    y = fminf(fmaxf(y, 0.0f), (float)(H_ - 1));
    x = fminf(fmaxf(x, 0.0f), (float)(W_ - 1));
    int y0 = (int)floorf(y); if (y0 > H_ - 1) y0 = H_ - 1;
    int x0 = (int)floorf(x); if (x0 > W_ - 1) x0 = W_ - 1;
    const int y1 = min(y0 + 1, H_ - 1);
    const int x1 = min(x0 + 1, W_ - 1);
    const float ly = y - (float)y0, lx = x - (float)x0;
    const float hy = 1.0f - ly,     hx = 1.0f - lx;
    const float m  = valid ? 0.25f : 0.0f;
    const __half2 wa = __float2half2_rn(hy * hx * m);   // (y0,x0)
    const __half2 wb = __float2half2_rn(hy * lx * m);   // (y0,x1)
    const __half2 wc = __float2half2_rn(ly * hx * m);   // (y1,x0)
    const __half2 wd = __float2half2_rn(ly * lx * m);   // (y1,x1)
    uint4 pw4;
    pw4.x = h2u(wa); pw4.y = h2u(wb); pw4.z = h2u(wc); pw4.w = h2u(wd);
    sWh[t] = pw4;
    const int pb = b * (H_ * W_);
    // offsets in uint4 units: pixel * (C_TOT/8)
    sIdx[t] = make_int4((pb + y0 * W_ + x0) * (C_TOT / 8),
                        (pb + y0 * W_ + x1) * (C_TOT / 8),
                        (pb + y1 * W_ + x0) * (C_TOT / 8),
                        (pb + y1 * W_ + x1) * (C_TOT / 8));
  }

  // orientation params (block-uniform)
  const float indf = th * 1.27323954473516268615f;   // * 8 / (2*pi)
  const float i0f  = floorf(indf);
  const float lv   = indf - i0f;
  const float rv   = 1.0f - lv;
  const int ind0 = __builtin_amdgcn_readfirstlane(((int)i0f) & 7);

  const int w  = t >> 6;                   // wave id 0..7
  const int l  = t & 63;
  const int cl = l & 31;                   // channel group: ch 8cl..8cl+7
  const bool hiHalf = (l & 32) != 0;       // false: corners A,C; true: B,D
  const int slot = 2 * cl + (hiHalf ? 1 : 0);

  __syncthreads();

  const __half2 zero = __float2half2_rn(0.0f);

  for (int i = w; i < NBIN; i += 8) {
    __half2 a01 = zero, a23 = zero, a45 = zero, a67 = zero;
#pragma unroll
    for (int s = 0; s < 4; ++s) {
      const int4  id = sIdx[i * 4 + s];
      const uint4 wt = sWh[i * 4 + s];
      const int b1 = hiHalf ? id.y : id.x;             // A | B
      const int b2 = hiHalf ? id.w : id.z;             // C | D
      const __half2 w1 = u2h2(hiHalf ? wt.y : wt.x);
      const __half2 w2 = u2h2(hiHalf ? wt.w : wt.z);
      const uint4 u1 = ft[b1 + cl];
      const uint4 u2 = ft[b2 + cl];
      a01 = __hfma2(u2h2(u1.x), w1, a01);
      a23 = __hfma2(u2h2(u1.y), w1, a23);
      a45 = __hfma2(u2h2(u1.z), w1, a45);
      a67 = __hfma2(u2h2(u1.w), w1, a67);
      a01 = __hfma2(u2h2(u2.x), w2, a01);
      a23 = __hfma2(u2h2(u2.y), w2, a23);
      a45 = __hfma2(u2h2(u2.z), w2, a45);
      a67 = __hfma2(u2h2(u2.w), w2, a67);
    }
    // combine corner-pair partials: lanes l and l^32 cover the same channels
    a01 = __hadd2(a01, u2h2(__shfl_xor(h2u(a01), 32)));
    a23 = __hadd2(a23, u2h2(__shfl_xor(h2u(a23), 32)));
    a45 = __hadd2(a45, u2h2(__shfl_xor(h2u(a45), 32)));
    a67 = __hadd2(a67, u2h2(__shfl_xor(h2u(a67), 32)));
    // 8 pooled channels fully in-lane: orientation mix needs no shuffles
    float p[8];
    float2 f;
    f = __half22float2(a01); p[0] = f.x; p[1] = f.y;
    f = __half22float2(a23); p[2] = f.x; p[3] = f.y;
    f = __half22float2(a45); p[4] = f.x; p[5] = f.y;
    f = __half22float2(a67); p[6] = f.x; p[7] = f.y;
    float r8[8];
#pragma unroll
    for (int jj = 0; jj < 8; ++jj) r8[jj] = rv * p[jj] + lv * p[(jj + 1) & 7];
    const unsigned q01 = h2u(__floats2half2_rn(r8[0], r8[1]));
    const unsigned q23 = h2u(__floats2half2_rn(r8[2], r8[3]));
    const unsigned q45 = h2u(__floats2half2_rn(r8[4], r8[5]));
    const unsigned q67 = h2u(__floats2half2_rn(r8[6], r8[7]));
    uint2 pk;
    pk.x = hiHalf ? q45 : q01;
    pk.y = hiHalf ? q67 : q23;
    obuf[i][slot ^ ((i >> 2) & 15)] = pk;
  }

  __syncthreads();

  // copy-out with rotation remap; contiguous 49 KB per block, nontemporal
  const __half* ob = (const __half*)obuf;
  float* outk = out + (size_t)k * PCH;
  for (int j4 = t; j4 < PCH / 4; j4 += 512) {
    const int jo = j4 * 4;
    f32x4 v;
#pragma unroll
    for (int e = 0; e < 4; ++e) {
      const int je   = jo + e;
      const int cout = je / NBIN;
      const int bb   = je - cout * NBIN;
      const int clds = (cout & ~7) | ((cout - ind0) & 7);
      const int sp   = (clds >> 2) ^ ((bb >> 2) & 15);
      v[e] = __half2float(ob[bb * 256 + sp * 4 + (clds & 3)]);
    }
    __builtin_nontemporal_store(v, (f32x4*)(outk + jo));
  }
}

// ---------------------------------------------------------------------------
// Fallback (NCHW f32, scalar) — used only if workspace is too small.
// ---------------------------------------------------------------------------
__global__ __launch_bounds__(256) void os2_rroialign_nchw(
    const float* __restrict__ ft, const float* __restrict__ rois,
    float* __restrict__ out) {
  __shared__ __align__(16) float outBuf[PCH];
  __shared__ int4   sIdx[NSAMP];
  __shared__ float4 sW[NSAMP];

  const int k = blockIdx.x;
  const int t = threadIdx.x;

  const float* roi = rois + (size_t)k * 6;
  const float th = roi[5];

  if (t < NSAMP) {
    const int   b  = (int)roi[0];
    const float cx = roi[1] * SCALE;
    const float cy = roi[2] * SCALE;
    const float rw = fmaxf(roi[3] * SCALE, 1.0f);
    const float rh = fmaxf(roi[4] * SCALE, 1.0f);
    const float binw = rw / (float)OUTS;
    const float binh = rh / (float)OUTS;
    const float cs = cosf(th);
    const float sn = sinf(th);
    const int bin = t >> 2;
    const int sub = t & 3;
    const int ph  = bin / 7;
    const int pw  = bin - ph * 7;
    const float fy = (float)ph + ((float)(sub >> 1) + 0.5f) * 0.5f;
    const float fx = (float)pw + ((float)(sub & 1)  + 0.5f) * 0.5f;
    const float yy = -rh * 0.5f + fy * binh;
    const float xx = -rw * 0.5f + fx * binw;
    float x = xx * cs - yy * sn + cx;
    float y = xx * sn + yy * cs + cy;
    const bool valid = (y >= -1.0f) && (y <= (float)H_) &&
                       (x >= -1.0f) && (x <= (float)W_);
    y = fminf(fmaxf(y, 0.0f), (float)(H_ - 1));
    x = fminf(fmaxf(x, 0.0f), (float)(W_ - 1));
    int y0 = (int)floorf(y); if (y0 > H_ - 1) y0 = H_ - 1;
    int x0 = (int)floorf(x); if (x0 > W_ - 1) x0 = W_ - 1;
    const int y1 = min(y0 + 1, H_ - 1);
    const int x1 = min(x0 + 1, W_ - 1);
    const float ly = y - (float)y0, lx = x - (float)x0;
    const float hy = 1.0f - ly,     hx = 1.0f - lx;
    const float m  = valid ? 0.25f : 0.0f;
    sW[t] = make_float4(hy * hx * m, hy * lx * m, ly * hx * m, ly * lx * m);
    const int cb = b * C_TOT * H_ * W_;
    sIdx[t] = make_int4(cb + y0 * W_ + x0, cb + y0 * W_ + x1,
                        cb + y1 * W_ + x0, cb + y1 * W_ + x1);
  }

  const float indf = th * 1.27323954473516268615f;
  const float i0f  = floorf(indf);
  const float lv   = indf - i0f;
  const float rv   = 1.0f - lv;
  const int ind0 = ((int)i0f) & 7;
  const int o    = t & 7;
  const int ir   = (o - ind0) & 7;
  const int irp  = (ir + 1) & 7;
  const int grp  = t & 56;
  const int chanOff = t * (H_ * W_);

  __syncthreads();

  for (int bin = 0; bin < NBIN; ++bin) {
    float acc = 0.0f;
#pragma unroll
    for (int s = 0; s < 4; ++s) {
      const int4   id = sIdx[bin * 4 + s];
      const float4 w  = sW[bin * 4 + s];
      acc = fmaf(w.x, ft[id.x + chanOff], acc);
      acc = fmaf(w.y, ft[id.y + chanOff], acc);
      acc = fmaf(w.z, ft[id.z + chanOff], acc);
      acc = fmaf(w.w, ft[id.w + chanOff], acc);
    }
    const float v1 = __shfl(acc, grp | ir,  64);
    const float v2 = __shfl(acc, grp | irp, 64);
    outBuf[t * NBIN + bin] = rv * v1 + lv * v2;
  }

  __syncthreads();
  const float4* ob4 = (const float4*)outBuf;
  float4* o4 = (float4*)(out + (size_t)k * PCH);
#pragma unroll 4
  for (int j = t; j < PCH / 4; j += 256) o4[j] = ob4[j];
}

// ---------------------------------------------------------------------------
extern "C" void kernel_launch(void* const* d_in, const int* in_sizes, int n_in,
                              void* d_out, int out_size, void* d_ws, size_t ws_size,
                              hipStream_t stream) {
  const float* features = (const float*)d_in[0];
  const float* rois     = (const float*)d_in[1];
  float* out            = (float*)d_out;
  const int K = in_sizes[1] / 6;

  const size_t ftBytes = (size_t)N_ * C_TOT * H_ * W_ * sizeof(ushort);
  const size_t permBytes = (size_t)((K + 255) & ~255) * sizeof(int);
  if (ws_size >= ftBytes + permBytes) {
    ushort* ftT = (ushort*)d_ws;
    int* perm   = (int*)((char*)d_ws + ftBytes);
    dim3 tb(64, 4);
    dim3 tg(W_ / 64, C_TOT / 64, N_ * H_);
    transpose_nchw_nhwc_f16<<<tg, tb, 0, stream>>>(features, ftT);
    if (K <= 1024) {
      sort_rois<<<1, 1024, 0, stream>>>(rois, K, perm);
    } else {
      identity_perm<<<(K + 255) / 256, 256, 0, stream>>>(K, perm);
    }
    os2_rroialign_v9<<<K, 512, 0, stream>>>((const uint4*)ftT, rois, perm, K, out);
  } else {
    os2_rroialign_nchw<<<K, 256, 0, stream>>>(features, rois, out);
  }
}

// Round 12
// 36.397 us; speedup vs baseline: 1.3398x; 1.3398x over previous
//
#include <hip/hip_runtime.h>
#include <hip/hip_bf16.h>
#include <hip/hip_fp16.h>
#include <math.h>

// Problem constants
constexpr int N_    = 2;
constexpr int C_TOT = 256;
constexpr int H_    = 128;
constexpr int W_    = 128;
constexpr int OUTS  = 7;
constexpr int NBIN  = OUTS * OUTS;          // 49
constexpr int NSAMP = NBIN * 4;             // 196 sample points per roi
constexpr int PCH   = C_TOT * NBIN;         // 12544 outputs per roi
constexpr float SCALE = 0.125f;

typedef float f32x4 __attribute__((ext_vector_type(4)));

__device__ __forceinline__ __half2 u2h2(unsigned u) {
  return *reinterpret_cast<__half2*>(&u);
}
__device__ __forceinline__ unsigned h2u(__half2 h) {
  return *reinterpret_cast<unsigned*>(&h);
}

// ---------------------------------------------------------------------------
// Fused kernel: blockIdx.z < N_*H_  -> NCHW f32 -> NHWC fp16 transpose slice
//               blockIdx.z == N_*H_ AND blockIdx.x==0 AND blockIdx.y==0
//                 -> ROI spatial counting sort (ONE block; R10's bug was 8
//                    x/y-sibling blocks racing on perm -> non-permutation)
// Sort key: (batch, 16px tileY, 16px tileX) of roi center -> 128 buckets.
// Within-bucket order is atomic-nondeterministic, but perm only routes rois
// to blocks; each roi's arithmetic and output slot are independent of its
// position -> d_out stays bit-deterministic.
// ---------------------------------------------------------------------------
__global__ __launch_bounds__(256) void transpose_and_sort(
    const float* __restrict__ in, ushort* __restrict__ out,
    const float* __restrict__ rois, int K, int* __restrict__ perm) {
  __shared__ float tile[64][65];
  __shared__ int cnt[128];
  __shared__ int base[128];

  const int nh = blockIdx.z;
  const int tx = threadIdx.x;
  const int ty = threadIdx.y;

  if (nh == N_ * H_) {
    if (blockIdx.x != 0 || blockIdx.y != 0) return;   // exactly ONE sorter
    const int t = ty * 64 + tx;
    if (t < 128) cnt[t] = 0;
    __syncthreads();
    for (int i = t; i < K; i += 256) {
      const float* roi = rois + (size_t)i * 6;
      const int b = (int)roi[0];
      int kx = (int)(roi[1] * SCALE * 0.0625f); kx = kx < 0 ? 0 : (kx > 7 ? 7 : kx);
      int ky = (int)(roi[2] * SCALE * 0.0625f); ky = ky < 0 ? 0 : (ky > 7 ? 7 : ky);
      atomicAdd(&cnt[(b << 6) | (ky << 3) | kx], 1);
    }
    __syncthreads();
    if (t == 0) {
      int s = 0;
      for (int i = 0; i < 128; ++i) { base[i] = s; s += cnt[i]; }
    }
    __syncthreads();
    for (int i = t; i < K; i += 256) {
      const float* roi = rois + (size_t)i * 6;
      const int b = (int)roi[0];
      int kx = (int)(roi[1] * SCALE * 0.0625f); kx = kx < 0 ? 0 : (kx > 7 ? 7 : kx);
      int ky = (int)(roi[2] * SCALE * 0.0625f); ky = ky < 0 ? 0 : (ky > 7 ? 7 : ky);
      const int pos = atomicAdd(&base[(b << 6) | (ky << 3) | kx], 1);
      perm[pos] = i;
    }
    return;
  }

  // ---- transpose slice ----
  const int n  = nh >> 7;
  const int h  = nh & 127;
  const int c0 = blockIdx.y * 64;
  const int w0 = blockIdx.x * 64;

  const float* src = in + (((size_t)n * C_TOT + c0) * H_ + h) * W_ + w0;
#pragma unroll
  for (int i = 0; i < 16; ++i) {
    const int c = i * 4 + ty;
    tile[c][tx] = src[(size_t)c * (H_ * W_) + tx];
  }
  __syncthreads();
  ushort* dst = out + (((size_t)n * H_ + h) * W_ + w0) * C_TOT + c0;
#pragma unroll
  for (int i = 0; i < 16; ++i) {
    const int w = i * 4 + ty;
    dst[(size_t)w * C_TOT + tx] = __half_as_ushort(__float2half(tile[tx][w]));
  }
}

// ---------------------------------------------------------------------------
// v11 main kernel. Compute identical to v8; sorted-roi indirection with
// bijective XCD chunking: block bid -> sorted pos j = chunk(bid%8) + bid/8,
// roi k = perm[j]. Each XCD's ~K/8 rois form a spatially contiguous slice
// (~2-5 MB of the 16.8 MB fp16 feature map) -> per-XCD L2 working-set fit.
// ---------------------------------------------------------------------------
__global__ __launch_bounds__(512, 8) void os2_rroialign_v11(
    const uint4* __restrict__ ft, const float* __restrict__ rois,
    const int* __restrict__ perm, int K, float* __restrict__ out) {
  __shared__ uint2 obuf[NBIN][64];         // 49*512 = 25088 B (fp16 x4)
  __shared__ int4  sIdx[NSAMP];            // 3136 B (uint4-unit pixel base)
  __shared__ uint4 sWh[NSAMP];             // 3136 B (4 dup-half2 weights)

  const int bid = blockIdx.x;
  const int q = K >> 3, r = K & 7;
  const int xcd = bid & 7;
  const int base = xcd < r ? xcd * (q + 1) : r * (q + 1) + (xcd - r) * q;
  const int j = base + (bid >> 3);
  const int k = perm[j];

  const int t = threadIdx.x;

  const float* roi = rois + (size_t)k * 6;
  const float th = roi[5];

  if (t < NSAMP) {
    const int   b  = (int)roi[0];
    const float cx = roi[1] * SCALE;
    const float cy = roi[2] * SCALE;
    const float rw = fmaxf(roi[3] * SCALE, 1.0f);
    const float rh = fmaxf(roi[4] * SCALE, 1.0f);
    const float binw = rw / (float)OUTS;
    const float binh = rh / (float)OUTS;
    const float cs = cosf(th);
    const float sn = sinf(th);

    const int bin = t >> 2;
    const int sub = t & 3;                  // iy*2 + ix
    const int ph  = bin / 7;
    const int pw  = bin - ph * 7;
    const float fy = (float)ph + ((float)(sub >> 1) + 0.5f) * 0.5f;
    const float fx = (float)pw + ((float)(sub & 1)  + 0.5f) * 0.5f;
    const float yy = -rh * 0.5f + fy * binh;
    const float xx = -rw * 0.5f + fx * binw;
    float x = xx * cs - yy * sn + cx;
    float y = xx * sn + yy * cs + cy;
    const bool valid = (y >= -1.0f) && (y <= (float)H_) &&
                       (x >= -1.0f) && (x <= (float)W_);
    y = fminf(fmaxf(y, 0.0f), (float)(H_ - 1));
    x = fminf(fmaxf(x, 0.0f), (float)(W_ - 1));
    int y0 = (int)floorf(y); if (y0 > H_ - 1) y0 = H_ - 1;
    int x0 = (int)floorf(x); if (x0 > W_ - 1) x0 = W_ - 1;
    const int y1 = min(y0 + 1, H_ - 1);
    const int x1 = min(x0 + 1, W_ - 1);
    const float ly = y - (float)y0, lx = x - (float)x0;
    const float hy = 1.0f - ly,     hx = 1.0f - lx;
    const float m  = valid ? 0.25f : 0.0f;
    const __half2 wa = __float2half2_rn(hy * hx * m);   // (y0,x0)
    const __half2 wb = __float2half2_rn(hy * lx * m);   // (y0,x1)
    const __half2 wc = __float2half2_rn(ly * hx * m);   // (y1,x0)
    const __half2 wd = __float2half2_rn(ly * lx * m);   // (y1,x1)
    uint4 pw4;
    pw4.x = h2u(wa); pw4.y = h2u(wb); pw4.z = h2u(wc); pw4.w = h2u(wd);
    sWh[t] = pw4;
    const int pb = b * (H_ * W_);
    // offsets in uint4 units: pixel * (C_TOT/8)
    sIdx[t] = make_int4((pb + y0 * W_ + x0) * (C_TOT / 8),
                        (pb + y0 * W_ + x1) * (C_TOT / 8),
                        (pb + y1 * W_ + x0) * (C_TOT / 8),
                        (pb + y1 * W_ + x1) * (C_TOT / 8));
  }

  // orientation params (block-uniform)
  const float indf = th * 1.27323954473516268615f;   // * 8 / (2*pi)
  const float i0f  = floorf(indf);
  const float lv   = indf - i0f;
  const float rv   = 1.0f - lv;
  const int ind0 = __builtin_amdgcn_readfirstlane(((int)i0f) & 7);

  const int w  = t >> 6;                   // wave id 0..7
  const int l  = t & 63;
  const int cl = l & 31;                   // channel group: ch 8cl..8cl+7
  const bool hiHalf = (l & 32) != 0;       // false: corners A,C; true: B,D
  const int slot = 2 * cl + (hiHalf ? 1 : 0);

  __syncthreads();

  const __half2 zero = __float2half2_rn(0.0f);

  for (int i = w; i < NBIN; i += 8) {
    __half2 a01 = zero, a23 = zero, a45 = zero, a67 = zero;
#pragma unroll
    for (int s = 0; s < 4; ++s) {
      const int4  id = sIdx[i * 4 + s];
      const uint4 wt = sWh[i * 4 + s];
      const int b1 = hiHalf ? id.y : id.x;             // A | B
      const int b2 = hiHalf ? id.w : id.z;             // C | D
      const __half2 w1 = u2h2(hiHalf ? wt.y : wt.x);
      const __half2 w2 = u2h2(hiHalf ? wt.w : wt.z);
      const uint4 u1 = ft[b1 + cl];
      const uint4 u2 = ft[b2 + cl];
      a01 = __hfma2(u2h2(u1.x), w1, a01);
      a23 = __hfma2(u2h2(u1.y), w1, a23);
      a45 = __hfma2(u2h2(u1.z), w1, a45);
      a67 = __hfma2(u2h2(u1.w), w1, a67);
      a01 = __hfma2(u2h2(u2.x), w2, a01);
      a23 = __hfma2(u2h2(u2.y), w2, a23);
      a45 = __hfma2(u2h2(u2.z), w2, a45);
      a67 = __hfma2(u2h2(u2.w), w2, a67);
    }
    // combine corner-pair partials: lanes l and l^32 cover the same channels
    a01 = __hadd2(a01, u2h2(__shfl_xor(h2u(a01), 32)));
    a23 = __hadd2(a23, u2h2(__shfl_xor(h2u(a23), 32)));
    a45 = __hadd2(a45, u2h2(__shfl_xor(h2u(a45), 32)));
    a67 = __hadd2(a67, u2h2(__shfl_xor(h2u(a67), 32)));
    // 8 pooled channels fully in-lane: orientation mix needs no shuffles
    float p[8];
    float2 f;
    f = __half22float2(a01); p[0] = f.x; p[1] = f.y;
    f = __half22float2(a23); p[2] = f.x; p[3] = f.y;
    f = __half22float2(a45); p[4] = f.x; p[5] = f.y;
    f = __half22float2(a67); p[6] = f.x; p[7] = f.y;
    float r8[8];
#pragma unroll
    for (int jj = 0; jj < 8; ++jj) r8[jj] = rv * p[jj] + lv * p[(jj + 1) & 7];
    const unsigned q01 = h2u(__floats2half2_rn(r8[0], r8[1]));
    const unsigned q23 = h2u(__floats2half2_rn(r8[2], r8[3]));
    const unsigned q45 = h2u(__floats2half2_rn(r8[4], r8[5]));
    const unsigned q67 = h2u(__floats2half2_rn(r8[6], r8[7]));
    uint2 pk;
    pk.x = hiHalf ? q45 : q01;
    pk.y = hiHalf ? q67 : q23;
    obuf[i][slot ^ ((i >> 2) & 15)] = pk;
  }

  __syncthreads();

  // copy-out with rotation remap; contiguous 49 KB per block, nontemporal
  const __half* ob = (const __half*)obuf;
  float* outk = out + (size_t)k * PCH;
  for (int j4 = t; j4 < PCH / 4; j4 += 512) {
    const int jo = j4 * 4;
    f32x4 v;
#pragma unroll
    for (int e = 0; e < 4; ++e) {
      const int je   = jo + e;
      const int cout = je / NBIN;
      const int bb   = je - cout * NBIN;
      const int clds = (cout & ~7) | ((cout - ind0) & 7);
      const int sp   = (clds >> 2) ^ ((bb >> 2) & 15);
      v[e] = __half2float(ob[bb * 256 + sp * 4 + (clds & 3)]);
    }
    __builtin_nontemporal_store(v, (f32x4*)(outk + jo));
  }
}

// ---------------------------------------------------------------------------
// Fallback (NCHW f32, scalar) — used only if workspace is too small.
// ---------------------------------------------------------------------------
__global__ __launch_bounds__(256) void os2_rroialign_nchw(
    const float* __restrict__ ft, const float* __restrict__ rois,
    float* __restrict__ out) {
  __shared__ __align__(16) float outBuf[PCH];
  __shared__ int4   sIdx[NSAMP];
  __shared__ float4 sW[NSAMP];

  const int k = blockIdx.x;
  const int t = threadIdx.x;

  const float* roi = rois + (size_t)k * 6;
  const float th = roi[5];

  if (t < NSAMP) {
    const int   b  = (int)roi[0];
    const float cx = roi[1] * SCALE;
    const float cy = roi[2] * SCALE;
    const float rw = fmaxf(roi[3] * SCALE, 1.0f);
    const float rh = fmaxf(roi[4] * SCALE, 1.0f);
    const float binw = rw / (float)OUTS;
    const float binh = rh / (float)OUTS;
    const float cs = cosf(th);
    const float sn = sinf(th);
    const int bin = t >> 2;
    const int sub = t & 3;
    const int ph  = bin / 7;
    const int pw  = bin - ph * 7;
    const float fy = (float)ph + ((float)(sub >> 1) + 0.5f) * 0.5f;
    const float fx = (float)pw + ((float)(sub & 1)  + 0.5f) * 0.5f;
    const float yy = -rh * 0.5f + fy * binh;
    const float xx = -rw * 0.5f + fx * binw;
    float x = xx * cs - yy * sn + cx;
    float y = xx * sn + yy * cs + cy;
    const bool valid = (y >= -1.0f) && (y <= (float)H_) &&
                       (x >= -1.0f) && (x <= (float)W_);
    y = fminf(fmaxf(y, 0.0f), (float)(H_ - 1));
    x = fminf(fmaxf(x, 0.0f), (float)(W_ - 1));
    int y0 = (int)floorf(y); if (y0 > H_ - 1) y0 = H_ - 1;
    int x0 = (int)floorf(x); if (x0 > W_ - 1) x0 = W_ - 1;
    const int y1 = min(y0 + 1, H_ - 1);
    const int x1 = min(x0 + 1, W_ - 1);
    const float ly = y - (float)y0, lx = x - (float)x0;
    const float hy = 1.0f - ly,     hx = 1.0f - lx;
    const float m  = valid ? 0.25f : 0.0f;
    sW[t] = make_float4(hy * hx * m, hy * lx * m, ly * hx * m, ly * lx * m);
    const int cb = b * C_TOT * H_ * W_;
    sIdx[t] = make_int4(cb + y0 * W_ + x0, cb + y0 * W_ + x1,
                        cb + y1 * W_ + x0, cb + y1 * W_ + x1);
  }

  const float indf = th * 1.27323954473516268615f;
  const float i0f  = floorf(indf);
  const float lv   = indf - i0f;
  const float rv   = 1.0f - lv;
  const int ind0 = ((int)i0f) & 7;
  const int o    = t & 7;
  const int ir   = (o - ind0) & 7;
  const int irp  = (ir + 1) & 7;
  const int grp  = t & 56;
  const int chanOff = t * (H_ * W_);

  __syncthreads();

  for (int bin = 0; bin < NBIN; ++bin) {
    float acc = 0.0f;
#pragma unroll
    for (int s = 0; s < 4; ++s) {
      const int4   id = sIdx[bin * 4 + s];
      const float4 w  = sW[bin * 4 + s];
      acc = fmaf(w.x, ft[id.x + chanOff], acc);
      acc = fmaf(w.y, ft[id.y + chanOff], acc);
      acc = fmaf(w.z, ft[id.z + chanOff], acc);
      acc = fmaf(w.w, ft[id.w + chanOff], acc);
    }
    const float v1 = __shfl(acc, grp | ir,  64);
    const float v2 = __shfl(acc, grp | irp, 64);
    outBuf[t * NBIN + bin] = rv * v1 + lv * v2;
  }

  __syncthreads();
  const float4* ob4 = (const float4*)outBuf;
  float4* o4 = (float4*)(out + (size_t)k * PCH);
#pragma unroll 4
  for (int j = t; j < PCH / 4; j += 256) o4[j] = ob4[j];
}

// ---------------------------------------------------------------------------
extern "C" void kernel_launch(void* const* d_in, const int* in_sizes, int n_in,
                              void* d_out, int out_size, void* d_ws, size_t ws_size,
                              hipStream_t stream) {
  const float* features = (const float*)d_in[0];
  const float* rois     = (const float*)d_in[1];
  float* out            = (float*)d_out;
  const int K = in_sizes[1] / 6;

  const size_t ftBytes = (size_t)N_ * C_TOT * H_ * W_ * sizeof(ushort);
  const size_t permBytes = (size_t)((K + 255) & ~255) * sizeof(int);
  if (ws_size >= ftBytes + permBytes) {
    ushort* ftT = (ushort*)d_ws;
    int* perm   = (int*)((char*)d_ws + ftBytes);
    dim3 tb(64, 4);
    dim3 tg(W_ / 64, C_TOT / 64, N_ * H_ + 1);   // +1 z-slice = roi sorter
    transpose_and_sort<<<tg, tb, 0, stream>>>(features, ftT, rois, K, perm);
    os2_rroialign_v11<<<K, 512, 0, stream>>>((const uint4*)ftT, rois, perm, K, out);
  } else {
    os2_rroialign_nchw<<<K, 256, 0, stream>>>(features, rois, out);
  }
}